// Round 3
// baseline (8212.440 us; speedup 1.0000x reference)
//
#include <hip/hip_runtime.h>
#include <hip/hip_bf16.h>
#include <hip/hip_cooperative_groups.h>

namespace cg = cooperative_groups;

#define T_STEPS 512
#define BSZ 64
#define NWG 64
#define NTHR 512

typedef __attribute__((ext_vector_type(4))) float f32x4;
typedef __attribute__((ext_vector_type(8))) short short8;

__device__ __forceinline__ short f2bf(float f) {
  __hip_bfloat16 h = __float2bfloat16(f);   // RNE
  return *reinterpret_cast<short*>(&h);
}
__device__ __forceinline__ unsigned bfbits(float f) {
  __hip_bfloat16 h = __float2bfloat16(f);
  return (unsigned)*reinterpret_cast<unsigned short*>(&h);
}

__global__ __launch_bounds__(NTHR, 2) void lstm_kernel(
    const float* __restrict__ X, const float* __restrict__ W,
    const float* __restrict__ Bv, float* __restrict__ Out,
    unsigned short* __restrict__ ring, unsigned int* __restrict__ ringW,
    unsigned int* __restrict__ flags)
{
  // B_x fragments: [kfrag 16][n 2][kgrp 4][col 16][8 bf16] = 32 KiB, conflict-free
  __shared__ char BxL[32768];

  const int tid  = threadIdx.x;
  const int wg   = blockIdx.x;        // h cols [8wg, 8wg+8)
  const int lane = tid & 63;
  const int wv   = tid >> 6;          // 8 waves: (m = wv>>1, n = wv&1)
  const int n    = wv & 1;
  const int m    = wv >> 1;
  const int c16  = lane & 15;         // packed col within N-tile: g*4 + hl
  const int g    = c16 >> 2;          // 0=f 1=i 2=g 3=o
  const int kgrp = lane >> 4;         // 0..3

  // ---- one-time: B_x (W rows 0..511, this WG's 32 gate cols) -> LDS frags ----
  for (int kk = tid >> 5; kk < 512; kk += 16) {
    const int c  = tid & 31;
    const int nn = c >> 4, cc = c & 15;
    const int gcol = (cc >> 2) * 512 + wg * 8 + nn * 4 + (cc & 3);
    const short v = f2bf(W[(size_t)kk * 2048 + gcol]);
    *(short*)(BxL + (kk >> 5) * 2048 + nn * 1024 + ((kk & 31) >> 3) * 256
              + cc * 16 + (kk & 7) * 2) = v;
  }

  // ---- one-time: B_h (W rows 512..1023) -> 16 persistent register fragments ----
  short8 Bh[16];
  {
    const int gcol = g * 512 + wg * 8 + n * 4 + (c16 & 3);
    const int kb   = 512 + kgrp * 8;
    #pragma unroll
    for (int f = 0; f < 16; ++f) {
      short8 v;
      #pragma unroll
      for (int j = 0; j < 8; ++j)
        v[j] = f2bf(W[(size_t)(kb + f * 32 + j) * 2048 + gcol]);
      Bh[f] = v;
    }
  }

  const int arow   = m * 16 + c16;            // A row (batch)
  const int akoff  = kgrp * 8;                // k offset inside K=32 frag
  const int bladdr = n * 1024 + kgrp * 256 + c16 * 16;
  const int hc     = wg * 8 + n * 4 + (c16 & 3);
  const float bias = Bv[g * 512 + hc];
  const int row0   = m * 16 + kgrp * 4;       // C/D rows row0..row0+3

  float cst[4] = {0.f, 0.f, 0.f, 0.f};

  __syncthreads();
  if (tid == 0)
    __hip_atomic_store(&flags[wg * 16], 0u, __ATOMIC_RELAXED, __HIP_MEMORY_SCOPE_AGENT);
  cg::this_grid().sync();

  for (int t = 0; t < T_STEPS; ++t) {
    f32x4 acc0 = {0.f, 0.f, 0.f, 0.f}, acc1 = {0.f, 0.f, 0.f, 0.f};

    // -------- phase A: x-GEMM(t) — independent of recurrence --------
    {
      const float* xa = X + (size_t)t * (BSZ * 512) + (size_t)arow * 512 + akoff;
      #pragma unroll
      for (int f = 0; f < 16; f += 2) {
        const float4 u0 = *(const float4*)(xa + f * 32);
        const float4 u1 = *(const float4*)(xa + f * 32 + 4);
        const float4 u2 = *(const float4*)(xa + f * 32 + 32);
        const float4 u3 = *(const float4*)(xa + f * 32 + 36);
        short8 a0, a1;
        a0[0] = f2bf(u0.x); a0[1] = f2bf(u0.y); a0[2] = f2bf(u0.z); a0[3] = f2bf(u0.w);
        a0[4] = f2bf(u1.x); a0[5] = f2bf(u1.y); a0[6] = f2bf(u1.z); a0[7] = f2bf(u1.w);
        a1[0] = f2bf(u2.x); a1[1] = f2bf(u2.y); a1[2] = f2bf(u2.z); a1[3] = f2bf(u2.w);
        a1[4] = f2bf(u3.x); a1[5] = f2bf(u3.y); a1[6] = f2bf(u3.z); a1[7] = f2bf(u3.w);
        const short8 b0 = *(const short8*)(BxL + f * 2048 + bladdr);
        const short8 b1 = *(const short8*)(BxL + (f + 1) * 2048 + bladdr);
        acc0 = __builtin_amdgcn_mfma_f32_16x16x32_bf16(a0, b0, acc0, 0, 0, 0);
        acc1 = __builtin_amdgcn_mfma_f32_16x16x32_bf16(a1, b1, acc1, 0, 0, 0);
      }
    }

    // -------- phase B: wait for h_{t-1}; phase C: h-GEMM --------
    if (t > 0) {
      if (wv == 0) {
        while (__hip_atomic_load(&flags[lane * 16], __ATOMIC_RELAXED,
                                 __HIP_MEMORY_SCOPE_AGENT) < (unsigned)t) {}
      }
      __syncthreads();
      __builtin_amdgcn_fence(__ATOMIC_ACQUIRE, "agent");  // kill stale L2 ring lines

      const unsigned short* ha = ring + (size_t)(((t - 1) & 1)) * 32768
                               + (size_t)arow * 512 + akoff;
      short8 A[16];
      #pragma unroll
      for (int f = 0; f < 16; ++f) A[f] = *(const short8*)(ha + f * 32);
      #pragma unroll
      for (int f = 0; f < 16; f += 2) {
        acc0 = __builtin_amdgcn_mfma_f32_16x16x32_bf16(A[f],     Bh[f],     acc0, 0, 0, 0);
        acc1 = __builtin_amdgcn_mfma_f32_16x16x32_bf16(A[f + 1], Bh[f + 1], acc1, 0, 0, 0);
      }
    }

    // -------- phase D: pointwise + stores + publish --------
    float hv[4], cnv[4];
    #pragma unroll
    for (int r = 0; r < 4; ++r) {
      const float pre = acc0[r] + acc1[r] + bias;
      const float e   = __expf((g == 2) ? -2.f * pre : -pre);
      const float act = (g == 2) ? (2.f / (1.f + e) - 1.f) : (1.f / (1.f + e));
      const float vi  = __shfl_xor(act, 4);    // f-lane <- i
      const float vg  = __shfl_xor(act, 8);    // f-lane <- g
      const float cn  = act * cst[r] + vi * vg;
      if (g == 0) cst[r] = cn;
      const float e2  = __expf(-2.f * cn);
      float tn = 2.f / (1.f + e2) - 1.f;
      tn = __shfl_xor(tn, 12);                 // o-lane <- tanh(c_new)
      hv[r]  = act * tn;                       // valid on o-lanes
      cnv[r] = cn;
    }

    float* outp = Out + ((size_t)t * BSZ + row0) * 512 + hc;
    #pragma unroll
    for (int r = 0; r < 4; ++r) {
      const unsigned hb = bfbits(hv[r]);
      const unsigned pb = (unsigned)__shfl_xor((int)hb, 1);  // partner col's bits
      if (g == 3) {
        outp[(size_t)r * 512] = hv[r];                       // fp32 output (cached)
        if (!(lane & 1)) {                                   // even col: pack pair
          const int row = row0 + r;
          const unsigned packed = (hb & 0xffffu) | (pb << 16);
          __hip_atomic_store(ringW + (t & 1) * 16384 + row * 256 + wg * 4 + n * 2
                               + ((lane & 2) >> 1),
                             packed, __ATOMIC_RELAXED, __HIP_MEMORY_SCOPE_AGENT);
        }
      }
    }
    if (t == T_STEPS - 1) {
      #pragma unroll
      for (int r = 0; r < 4; ++r) {
        const int row = row0 + r;
        if (g == 3) Out[(size_t)T_STEPS * BSZ * 512 + (size_t)row * 512 + hc] = hv[r];  // hx
        if (g == 0) Out[(size_t)T_STEPS * BSZ * 512 + BSZ * 512 + (size_t)row * 512 + hc] = cnv[r]; // cx
      }
    }

    __syncthreads();   // drains ring stores (vmcnt) before publish
    if (tid == 0)
      __hip_atomic_store(&flags[wg * 16], (unsigned)(t + 1),
                         __ATOMIC_RELEASE, __HIP_MEMORY_SCOPE_AGENT);
  }
}

extern "C" void kernel_launch(void* const* d_in, const int* in_sizes, int n_in,
                              void* d_out, int out_size, void* d_ws, size_t ws_size,
                              hipStream_t stream) {
  const float* X  = (const float*)d_in[0];
  const float* W  = (const float*)d_in[1];
  const float* Bv = (const float*)d_in[2];
  float* Out = (float*)d_out;
  unsigned short* ring  = (unsigned short*)d_ws;                    // 2 x 64 KiB bf16 h
  unsigned int*   ringW = (unsigned int*)d_ws;
  unsigned int*   flags = (unsigned int*)((char*)d_ws + 131072);    // 64 x 64 B

  void* args[7];
  args[0] = (void*)&X;
  args[1] = (void*)&W;
  args[2] = (void*)&Bv;
  args[3] = (void*)&Out;
  args[4] = (void*)&ring;
  args[5] = (void*)&ringW;
  args[6] = (void*)&flags;
  hipLaunchCooperativeKernel((const void*)lstm_kernel, dim3(NWG), dim3(NTHR),
                             args, 0, stream);
}

// Round 5
// 3120.354 us; speedup vs baseline: 2.6319x; 2.6319x over previous
//
#include <hip/hip_runtime.h>
#include <hip/hip_bf16.h>
#include <hip/hip_cooperative_groups.h>

namespace cg = cooperative_groups;

#define T_STEPS 512
// ws layout: Xf bf16 frag-major [0,32MiB) | ring 2x64KiB | flags 64x64B
#define RING_OFF 33554432u
#define FLAG_OFF 33685504u
#define WS_NEED  33689600u

typedef __attribute__((ext_vector_type(4))) float f32x4;
typedef __attribute__((ext_vector_type(8))) short short8;
typedef __attribute__((ext_vector_type(4))) unsigned int u32x4;

__device__ __forceinline__ short f2bf(float f) {
  __hip_bfloat16 h = __float2bfloat16(f);   // RNE
  return *reinterpret_cast<short*>(&h);
}
__device__ __forceinline__ unsigned bfbits(float f) {
  __hip_bfloat16 h = __float2bfloat16(f);
  return (unsigned)*reinterpret_cast<unsigned short*>(&h);
}
__device__ __forceinline__ short8 as_s8(u32x4 v) {
  union { u32x4 u; short8 s; } x; x.u = v; return x.s;
}

__global__ __launch_bounds__(512, 2) void lstm_kernel(
    const float* __restrict__ X, const float* __restrict__ W,
    const float* __restrict__ Bv, float* __restrict__ Out,
    char* __restrict__ ws)
{
  const int tid  = threadIdx.x;
  const int wg   = blockIdx.x;      // 0..63 -> h cols [8wg, 8wg+8)
  const int lane = tid & 63;
  const int wv   = tid >> 6;        // 8 waves: m = wv>>1 (rows 16m..), n = wv&1 (4-col half)
  const int m    = wv >> 1;
  const int n    = wv & 1;
  const int c16  = lane & 15;       // packed col = g*4 + q
  const int kgrp = lane >> 4;
  const int gg   = c16 >> 2;        // 0=f 1=i 2=g 3=o
  const int q    = c16 & 3;

  char*     Xf    = ws;
  char*     ring  = ws + RING_OFF;
  unsigned* flags = (unsigned*)(ws + FLAG_OFF);

  // ---- zero my flag (before grid sync; robust across graph replays) ----
  if (tid == 0)
    __hip_atomic_store(&flags[wg * 16], 0u, __ATOMIC_RELAXED, __HIP_MEMORY_SCOPE_AGENT);

  // ---- one-time: X (fp32) -> Xf (bf16, A-frag-major) ----
  // element (t,row,k): addr = t*65536 + (row>>4)*16384 + (k>>5)*1024
  //                         + (((k>>3)&3)<<4 | (row&15))*16 + (k&7)*2
  for (int id = wg * 512 + tid; id < 512 * 64 * 64; id += 64 * 512) {
    const int c8  = id & 63;         // k-chunk of 8
    const int row = (id >> 6) & 63;
    const int t   = id >> 12;
    const float* xp = X + ((size_t)(t * 64 + row)) * 512 + c8 * 8;
    const float4 a = *(const float4*)xp;
    const float4 b = *(const float4*)(xp + 4);
    short8 v;
    v[0]=f2bf(a.x); v[1]=f2bf(a.y); v[2]=f2bf(a.z); v[3]=f2bf(a.w);
    v[4]=f2bf(b.x); v[5]=f2bf(b.y); v[6]=f2bf(b.z); v[7]=f2bf(b.w);
    *(short8*)(Xf + (size_t)t * 65536 + (row >> 4) * 16384 + (c8 >> 2) * 1024
               + ((((c8 & 3) << 4) | (row & 15))) * 16) = v;
  }
  __threadfence();                                   // write back dirty L2 (Xf)
  cg::this_grid().sync();
  __builtin_amdgcn_fence(__ATOMIC_ACQUIRE, "agent"); // one-time inv of stale clean lines

  // ---- W -> 32 persistent B-fragments (128 VGPRs): k = kk*32 + kgrp*8 + j ----
  const int gcol = gg * 512 + wg * 8 + n * 4 + q;    // actual W column
  short8 B[32];
  #pragma unroll
  for (int kk = 0; kk < 32; ++kk) {
    short8 v;
    #pragma unroll
    for (int j = 0; j < 8; ++j)
      v[j] = f2bf(W[(size_t)(kk * 32 + kgrp * 8 + j) * 2048 + gcol]);
    B[kk] = v;
  }
  const float bias = Bv[gcol];

  float cst[4] = {0.f, 0.f, 0.f, 0.f};

  for (int t = 0; t < T_STEPS; ++t) {
    f32x4 ac0 = {0,0,0,0}, ac1 = {0,0,0,0}, ac2 = {0,0,0,0}, ac3 = {0,0,0,0};

    // -------- x-phase (cached loads from Xf; independent of recurrence) --------
    {
      const char* xa = Xf + (size_t)t * 65536 + m * 16384 + lane * 16;
      #pragma unroll
      for (int f = 0; f < 16; f += 4) {
        const short8 a0 = *(const short8*)(xa + (size_t)f * 1024);
        const short8 a1 = *(const short8*)(xa + (size_t)f * 1024 + 1024);
        const short8 a2 = *(const short8*)(xa + (size_t)f * 1024 + 2048);
        const short8 a3 = *(const short8*)(xa + (size_t)f * 1024 + 3072);
        ac0 = __builtin_amdgcn_mfma_f32_16x16x32_bf16(a0, B[f],     ac0, 0, 0, 0);
        ac1 = __builtin_amdgcn_mfma_f32_16x16x32_bf16(a1, B[f + 1], ac1, 0, 0, 0);
        ac2 = __builtin_amdgcn_mfma_f32_16x16x32_bf16(a2, B[f + 2], ac2, 0, 0, 0);
        ac3 = __builtin_amdgcn_mfma_f32_16x16x32_bf16(a3, B[f + 3], ac3, 0, 0, 0);
      }
    }

    // -------- poll (round-1-verified agent-atomic protocol) + h-phase --------
    if (t > 0) {
      if (wv == 0) {
        while (__hip_atomic_load(&flags[lane * 16], __ATOMIC_RELAXED,
                                 __HIP_MEMORY_SCOPE_AGENT) < (unsigned)t) {}
      }
      __syncthreads();

      const char* hp0 = ring + (size_t)((t - 1) & 1) * 65536 + m * 16384 + lane * 16;
      const char* hp1 = hp0 + 4096;
      const char* hp2 = hp0 + 8192;
      const char* hp3 = hp0 + 12288;
      u32x4 h0,h1,h2,h3,h4,h5,h6,h7,h8,h9,h10,h11,h12,h13,h14,h15;
      // sc0 sc1: bypass L1+L2, read LLC directly -> coherent with agent-release, no fence
      #define LDR(base, off, vv) \
        asm volatile("global_load_dwordx4 %0, %1, off offset:" off " sc0 sc1" \
                     : "=v"(vv) : "v"(base))
      LDR(hp0, "0", h0);  LDR(hp0, "1024", h1);  LDR(hp0, "2048", h2);  LDR(hp0, "3072", h3);
      LDR(hp1, "0", h4);  LDR(hp1, "1024", h5);  LDR(hp1, "2048", h6);  LDR(hp1, "3072", h7);
      LDR(hp2, "0", h8);  LDR(hp2, "1024", h9);  LDR(hp2, "2048", h10); LDR(hp2, "3072", h11);
      LDR(hp3, "0", h12); LDR(hp3, "1024", h13); LDR(hp3, "2048", h14); LDR(hp3, "3072", h15);
      #undef LDR
      asm volatile("s_waitcnt vmcnt(0)" ::: "memory");
      __builtin_amdgcn_sched_barrier(0);
      ac0 = __builtin_amdgcn_mfma_f32_16x16x32_bf16(as_s8(h0),  B[16], ac0, 0, 0, 0);
      ac1 = __builtin_amdgcn_mfma_f32_16x16x32_bf16(as_s8(h1),  B[17], ac1, 0, 0, 0);
      ac2 = __builtin_amdgcn_mfma_f32_16x16x32_bf16(as_s8(h2),  B[18], ac2, 0, 0, 0);
      ac3 = __builtin_amdgcn_mfma_f32_16x16x32_bf16(as_s8(h3),  B[19], ac3, 0, 0, 0);
      ac0 = __builtin_amdgcn_mfma_f32_16x16x32_bf16(as_s8(h4),  B[20], ac0, 0, 0, 0);
      ac1 = __builtin_amdgcn_mfma_f32_16x16x32_bf16(as_s8(h5),  B[21], ac1, 0, 0, 0);
      ac2 = __builtin_amdgcn_mfma_f32_16x16x32_bf16(as_s8(h6),  B[22], ac2, 0, 0, 0);
      ac3 = __builtin_amdgcn_mfma_f32_16x16x32_bf16(as_s8(h7),  B[23], ac3, 0, 0, 0);
      ac0 = __builtin_amdgcn_mfma_f32_16x16x32_bf16(as_s8(h8),  B[24], ac0, 0, 0, 0);
      ac1 = __builtin_amdgcn_mfma_f32_16x16x32_bf16(as_s8(h9),  B[25], ac1, 0, 0, 0);
      ac2 = __builtin_amdgcn_mfma_f32_16x16x32_bf16(as_s8(h10), B[26], ac2, 0, 0, 0);
      ac3 = __builtin_amdgcn_mfma_f32_16x16x32_bf16(as_s8(h11), B[27], ac3, 0, 0, 0);
      ac0 = __builtin_amdgcn_mfma_f32_16x16x32_bf16(as_s8(h12), B[28], ac0, 0, 0, 0);
      ac1 = __builtin_amdgcn_mfma_f32_16x16x32_bf16(as_s8(h13), B[29], ac1, 0, 0, 0);
      ac2 = __builtin_amdgcn_mfma_f32_16x16x32_bf16(as_s8(h14), B[30], ac2, 0, 0, 0);
      ac3 = __builtin_amdgcn_mfma_f32_16x16x32_bf16(as_s8(h15), B[31], ac3, 0, 0, 0);
    }

    // -------- pointwise (round-1-verified 16x16 layout, shfl 4/8/12) --------
    float hv[4], cnv[4];
    #pragma unroll
    for (int r = 0; r < 4; ++r) {
      const float pre = ac0[r] + ac1[r] + ac2[r] + ac3[r] + bias;
      const float e   = __expf((gg == 2) ? -2.f * pre : -pre);
      const float act = (gg == 2) ? (2.f / (1.f + e) - 1.f) : (1.f / (1.f + e));
      const float vi  = __shfl_xor(act, 4);     // f-lane <- i
      const float vg  = __shfl_xor(act, 8);     // f-lane <- g
      const float cn  = act * cst[r] + vi * vg; // valid on f-lanes
      if (gg == 0) cst[r] = cn;
      const float e2  = __expf(-2.f * cn);
      float tn = 2.f / (1.f + e2) - 1.f;
      tn = __shfl_xor(tn, 12);                  // o-lane <- tanh(c_new)
      hv[r]  = act * tn;                        // valid on o-lanes
      cnv[r] = cn;
    }

    const int hc = wg * 8 + n * 4 + q;
    if (gg == 3) {
      float* op = Out + ((size_t)t * 64 + m * 16 + kgrp * 4) * 512 + hc;
      char*  rp = ring + (size_t)(t & 1) * 65536 + m * 16384 + (wg >> 2) * 1024
                + (((wg & 3) << 4) + kgrp * 4) * 16 + (n * 4 + q) * 2;
      #pragma unroll
      for (int r = 0; r < 4; ++r) {
        const unsigned hb = bfbits(hv[r]);
        const unsigned pb = (unsigned)__shfl_xor((int)hb, 1);  // partner col
        op[(size_t)r * 512] = hv[r];                           // fp32 output (cached)
        if (!(q & 1))                                          // even col packs the pair
          __hip_atomic_store((unsigned*)(rp + r * 16),
                             (hb & 0xffffu) | (pb << 16),
                             __ATOMIC_RELAXED, __HIP_MEMORY_SCOPE_AGENT);
      }
      if (t == T_STEPS - 1) {
        #pragma unroll
        for (int r = 0; r < 4; ++r)
          Out[16777216u + (size_t)(m * 16 + kgrp * 4 + r) * 512 + hc] = hv[r];     // hx
      }
    }
    if (gg == 0 && t == T_STEPS - 1) {
      #pragma unroll
      for (int r = 0; r < 4; ++r)
        Out[16777216u + 32768u + (size_t)(m * 16 + kgrp * 4 + r) * 512 + hc] = cnv[r]; // cx
    }

    __syncthreads();   // all waves' ring stores drained (vmcnt) before publish
    if (tid == 0)
      __hip_atomic_store(&flags[wg * 16], (unsigned)(t + 1),
                         __ATOMIC_RELEASE, __HIP_MEMORY_SCOPE_AGENT);
  }
}

extern "C" void kernel_launch(void* const* d_in, const int* in_sizes, int n_in,
                              void* d_out, int out_size, void* d_ws, size_t ws_size,
                              hipStream_t stream) {
  if (ws_size < (size_t)WS_NEED) return;

  const float* X  = (const float*)d_in[0];
  const float* W  = (const float*)d_in[1];
  const float* Bv = (const float*)d_in[2];
  float* Out = (float*)d_out;
  char*  ws  = (char*)d_ws;

  void* args[5];
  args[0] = (void*)&X;
  args[1] = (void*)&W;
  args[2] = (void*)&Bv;
  args[3] = (void*)&Out;
  args[4] = (void*)&ws;
  hipLaunchCooperativeKernel((const void*)lstm_kernel, dim3(64), dim3(512),
                             args, 0, stream);
}